// Round 1
// 5428.389 us; speedup vs baseline: 1.3910x; 1.3910x over previous
//
#include <hip/hip_runtime.h>
#include <hip/hip_bf16.h>

#define Bb    128
#define Ss    256
#define Ff    4
#define Vv    1024
#define Ee    512
#define Hh    1024
#define FourH 4096
#define Mrows (Bb * Ss)
#define NBLK  192      // 64 layer-0 WGs + 128 layer-1 WGs
#define NGRP  8
#define GSZ   (NBLK / NGRP)   // 24

typedef _Float16 f16;
typedef __attribute__((ext_vector_type(8))) _Float16 half8;
typedef __attribute__((ext_vector_type(4))) float f32x4;

// ---------------------------------------------------------------------------
__global__ void cvt_f16_kernel(const float* __restrict__ s, f16* __restrict__ d, int n) {
    int i = blockIdx.x * blockDim.x + threadIdx.x;
    int stride = gridDim.x * blockDim.x;
    for (; i < n; i += stride) d[i] = (f16)s[i];
}

__global__ void bias_combine_kernel(const float* __restrict__ a, const float* __restrict__ b,
                                    const float* __restrict__ c, const float* __restrict__ d,
                                    float* __restrict__ o0, float* __restrict__ o1) {
    int i = blockIdx.x * blockDim.x + threadIdx.x;
    if (i < FourH) o0[i] = a[i] + b[i];
    else if (i < 2 * FourH) { int j = i - FourH; o1[j] = c[j] + d[j]; }
}

// Embedding: sum over F tables -> f16 [S, B, E] (time-major)
__global__ void emb_kernel(const int* __restrict__ x, const float* __restrict__ emb,
                           f16* __restrict__ out) {
    int r = blockIdx.x;
    int t = threadIdx.x;
    int b = r / Ss, s = r % Ss;
    const int* xr = x + (size_t)r * Ff;
    const float* e0 = emb + (size_t)xr[0] * Ee;
    const float* e1 = emb + (size_t)(Vv + xr[1]) * Ee;
    const float* e2 = emb + (size_t)(2 * Vv + xr[2]) * Ee;
    const float* e3 = emb + (size_t)(3 * Vv + xr[3]) * Ee;
    f16* orow = out + (size_t)(s * Bb + b) * Ee;
    for (int e = t; e < Ee; e += 256) orow[e] = (f16)(e0[e] + e1[e] + e2[e] + e3[e]);
}

// ---------------------------------------------------------------------------
// C[M,N] = A[M,K] @ B[N,K]^T + bias[N]  (f16 in, f16 out, fp32 accum)
#define BM 128
#define BN 128
#define BK 32
#define LDP 40

__global__ __launch_bounds__(256) void gemm_bt_kernel(
    const f16* __restrict__ A, const f16* __restrict__ Bw,
    const float* __restrict__ bias, f16* __restrict__ C,
    int M, int N, int K)
{
    __shared__ f16 As[BM * LDP];
    __shared__ f16 Bs[BN * LDP];
    int tid  = threadIdx.x;
    int n0   = blockIdx.x * BN;
    int m0   = blockIdx.y * BM;
    int w    = tid >> 6, lane = tid & 63;
    int wm   = (w >> 1) * 64, wn = (w & 1) * 64;
    int lrow = lane & 15, koff = lane >> 4;

    f32x4 acc[4][4] = {};

    for (int kb = 0; kb < K; kb += BK) {
        __syncthreads();
        #pragma unroll
        for (int h = 0; h < 2; ++h) {
            int ch  = tid + h * 256;
            int row = ch >> 2;
            int cc  = (ch & 3) * 8;
            *reinterpret_cast<uint4*>(&As[row * LDP + cc]) =
                *reinterpret_cast<const uint4*>(A + (size_t)(m0 + row) * K + kb + cc);
            *reinterpret_cast<uint4*>(&Bs[row * LDP + cc]) =
                *reinterpret_cast<const uint4*>(Bw + (size_t)(n0 + row) * K + kb + cc);
        }
        __syncthreads();
        half8 af[4], bf[4];
        #pragma unroll
        for (int mt = 0; mt < 4; ++mt)
            af[mt] = *reinterpret_cast<const half8*>(&As[(wm + mt * 16 + lrow) * LDP + koff * 8]);
        #pragma unroll
        for (int nt = 0; nt < 4; ++nt)
            bf[nt] = *reinterpret_cast<const half8*>(&Bs[(wn + nt * 16 + lrow) * LDP + koff * 8]);
        #pragma unroll
        for (int mt = 0; mt < 4; ++mt)
            #pragma unroll
            for (int nt = 0; nt < 4; ++nt)
                acc[mt][nt] = __builtin_amdgcn_mfma_f32_16x16x32_f16(af[mt], bf[nt], acc[mt][nt], 0, 0, 0);
    }

    #pragma unroll
    for (int mt = 0; mt < 4; ++mt)
        #pragma unroll
        for (int nt = 0; nt < 4; ++nt) {
            int col = n0 + wn + nt * 16 + lrow;
            float bv = bias[col];
            #pragma unroll
            for (int r = 0; r < 4; ++r) {
                int rowg = m0 + wm + mt * 16 + koff * 4 + r;
                C[(size_t)rowg * N + col] = (f16)(acc[mt][nt][r] + bv);
            }
        }
}

// ---------------------------------------------------------------------------
__device__ __forceinline__ void gload_lds16(const void* g, void* l) {
    __builtin_amdgcn_global_load_lds((const __attribute__((address_space(1))) void*)g,
                                     (__attribute__((address_space(3))) void*)l, 16, 0, 0);
}

__device__ __forceinline__ unsigned aload(unsigned* p) {
    return __hip_atomic_load(p, __ATOMIC_RELAXED, __HIP_MEMORY_SCOPE_AGENT);
}

// 2-level device-scope grid barrier. Monotonic generation counters (no reset
// needed; survives the 2-launch split). Padded cachelines:
//   bar[g*32]        : group-g arrival count        (g = 0..7)
//   bar[(8+g)*32]    : group-g release (generation) count
//   bar[16*32]       : root arrival count
//   bar[17*32]       : root release (generation) count
__device__ __forceinline__ void grid_sync(unsigned* bar, int wg) {
    __syncthreads();
    if (threadIdx.x == 0) {
        const int g = wg & (NGRP - 1);
        unsigned* arr  = bar + g * 32;
        unsigned* rel  = bar + (8 + g) * 32;
        unsigned* root = bar + 16 * 32;
        unsigned* rrel = bar + 17 * 32;
        __threadfence();
        unsigned a   = atomicAdd(arr, 1u);
        unsigned gen = a / (unsigned)GSZ;
        if (a % (unsigned)GSZ == (unsigned)(GSZ - 1)) {       // group leader this gen
            unsigned r = atomicAdd(root, 1u);
            if (r % (unsigned)NGRP == (unsigned)(NGRP - 1)) {
                atomicAdd(rrel, 1u);                          // global release
            } else {
                while (aload(rrel) < gen + 1u) __builtin_amdgcn_s_sleep(2);
            }
            atomicAdd(rel, 1u);                               // group release
        }
        while (aload(rel) < gen + 1u) __builtin_amdgcn_s_sleep(2);
        __threadfence();
    }
    __syncthreads();
}

__device__ __forceinline__ float sigm(float v) { return 1.f / (1.f + __expf(-v)); }

// ---------------------------------------------------------------------------
// Persistent fused 2-layer LSTM scan. Iteration i: L0 computes step i (i<256),
// L1 computes step i-1 (i>=1). Weights held in registers for the whole launch.
//
// New structure vs previous version:
//  * splitK across waves + nt=2 col-tiles per wave: each ds_read_b128
//    A-fragment feeds TWO MFMAs (A-read traffic halved).
//  * staging via async global_load_lds (16B) with XOR seg-swizzle
//    (seg ^= row&7) applied to the GLOBAL SOURCE address and the LDS READ
//    address; LDS destination stays linear (HW requirement). Double-buffered:
//    slice j+1 is issued right after the barrier and drains at the NEXT
//    barrier (the compiler's vmcnt(0) before s_barrier is the wait).
//  * partial sums combined through ep[] (aliased onto the staging buffers,
//    guarded by barriers).
// WGs 0..63: L0 (16 units, K=1024, kh-split x2). WGs 64..191: L1 (8 units,
// K=2048 = [wih1;whh1], kq-split x4).
__global__ __launch_bounds__(512, 2) void scan_kernel(
    const f16* __restrict__ gx0,    // gates0 chunk base [nt][128][4096]
    int t_begin, int t_end,
    const f16* __restrict__ wih1, const f16* __restrict__ whh0,
    const f16* __restrict__ whh1, const float* __restrict__ bias1,
    f16* __restrict__ h0a, f16* __restrict__ h0b,
    f16* __restrict__ h1a, f16* __restrict__ h1b,
    float* __restrict__ c0, float* __restrict__ c1,
    float* __restrict__ out, unsigned* __restrict__ bar)
{
    __shared__ __align__(1024) char smem[131072];   // 128 KB: 2 x 64 KB staging dbuf
    float* ep = (float*)smem;                       // epilogue partials (aliased)

    const int tid  = threadIdx.x;
    const int wg   = blockIdx.x;
    const int lane = tid & 63;
    const int w    = tid >> 6;
    const int lrow = lane & 15, koff = lane >> 4;
    // read-swizzle precompute: s*16 = ((kt2*64) ^ r34) | kxy
    const int kxy = (koff ^ (lane & 3)) << 4;
    const int r34 = (lane & 4) << 4;

    if (wg < 64) {
        // ---------------- Layer 0: 16 units, K=1024, waves = m(2) x gp(2) x kh(2)
        const int u0 = wg * 16;
        const int m  = w & 1, gp = (w >> 1) & 1, kh = w >> 2;
        const int wm = m * 64;

        half8 wreg[16][2];                 // [j*4+kt2][nt]  (K window kh*512 + t*32)
        #pragma unroll
        for (int t = 0; t < 16; ++t)
            #pragma unroll
            for (int nt = 0; nt < 2; ++nt)
                wreg[t][nt] = *(const half8*)(whh0
                    + (size_t)((gp * 2 + nt) * Hh + u0 + lrow) * Hh
                    + kh * 512 + t * 32 + koff * 8);

        float creg[4];
        #pragma unroll
        for (int q = 0; q < 4; ++q) {
            int p = tid + q * 512, row = p >> 4, uu = p & 15;
            creg[q] = c0[row * Hh + u0 + uu];
        }

        // staging: instr t stages 4 rows (r0 = ((w&3)*8+t)*4); lane l covers
        // row r0+(l>>4), seg l&15. r0&7 = (t&1)*4 -> two per-lane offsets.
        const int Rl   = lane >> 4;
        const int segl = lane & 15;
        const unsigned offp0 = Rl * 2048 + (((segl ^ Rl) & 15) << 4);
        const unsigned offp1 = Rl * 2048 + (((segl ^ (Rl + 4)) & 15) << 4);
        const int arow = (wm + lrow) * 256;

        for (int i = t_begin; i < t_end; ++i) {
            if (i < 256) {
                const f16* hp = (i & 1) ? h0a : h0b;   // h0[i-1]
                f16*       hw = (i & 1) ? h0b : h0a;   // h0[i]
                const f16* gx = gx0 + (size_t)(i - t_begin) * (Bb * FourH);
                const char* hb = (const char*)hp;

                // prefetch gate inputs (latency hides under slice-0 staging)
                f16 gxr[4][4];
                #pragma unroll
                for (int q = 0; q < 4; ++q) {
                    int p = tid + q * 512, row = p >> 4, uu = p & 15;
                    const f16* gr = gx + (size_t)row * FourH + u0 + uu;
                    gxr[q][0] = gr[0];      gxr[q][1] = gr[Hh];
                    gxr[q][2] = gr[2 * Hh]; gxr[q][3] = gr[3 * Hh];
                }

                // stage slice 0 -> buf 0
                #pragma unroll
                for (int t = 0; t < 8; ++t) {
                    int r0 = ((w & 3) * 8 + t) * 4;
                    gload_lds16(hb + r0 * 2048 + kh * 1024 + ((t & 1) ? offp1 : offp0),
                                smem + kh * 32768 + ((w & 3) * 8 + t) * 1024);
                }

                f32x4 acc[4][2] = {};
                int cur = 0;
                #pragma unroll
                for (int j = 0; j < 4; ++j) {
                    asm volatile("s_waitcnt vmcnt(0)" ::: "memory");
                    __syncthreads();       // slice j staged everywhere; prev reads done
                    if (j < 3) {
                        int colb = kh * 1024 + (j + 1) * 256;
                        char* lb = smem + (cur ^ 1) * 65536 + kh * 32768;
                        #pragma unroll
                        for (int t = 0; t < 8; ++t) {
                            int r0 = ((w & 3) * 8 + t) * 4;
                            gload_lds16(hb + r0 * 2048 + colb + ((t & 1) ? offp1 : offp0),
                                        lb + ((w & 3) * 8 + t) * 1024);
                        }
                    }
                    const char* rb = (const char*)smem + cur * 65536 + kh * 32768;
                    #pragma unroll
                    for (int kt2 = 0; kt2 < 4; ++kt2) {
                        int s16 = ((kt2 * 64) ^ r34) | kxy;
                        half8 a[4];
                        #pragma unroll
                        for (int mt = 0; mt < 4; ++mt)
                            a[mt] = *(const half8*)(rb + arow + mt * 4096 + s16);
                        #pragma unroll
                        for (int mt = 0; mt < 4; ++mt) {
                            acc[mt][0] = __builtin_amdgcn_mfma_f32_16x16x32_f16(a[mt], wreg[j * 4 + kt2][0], acc[mt][0], 0, 0, 0);
                            acc[mt][1] = __builtin_amdgcn_mfma_f32_16x16x32_f16(a[mt], wreg[j * 4 + kt2][1], acc[mt][1], 0, 0, 0);
                        }
                    }
                    cur ^= 1;
                }
                __syncthreads();           // all staging reads done before ep overwrite
                // ep[((kh*4+g)*128+row)*20 + unit]
                #pragma unroll
                for (int mt = 0; mt < 4; ++mt)
                    #pragma unroll
                    for (int nt = 0; nt < 2; ++nt) {
                        int g = gp * 2 + nt;
                        int rowb = wm + mt * 16 + koff * 4;
                        #pragma unroll
                        for (int r = 0; r < 4; ++r)
                            ep[((kh * 4 + g) * 128 + rowb + r) * 20 + lrow] = acc[mt][nt][r];
                    }
                __syncthreads();
                #pragma unroll
                for (int q = 0; q < 4; ++q) {
                    int p = tid + q * 512, row = p >> 4, uu = p & 15;
                    float ipre = ep[(0 * 128 + row) * 20 + uu] + ep[(4 * 128 + row) * 20 + uu] + (float)gxr[q][0];
                    float fpre = ep[(1 * 128 + row) * 20 + uu] + ep[(5 * 128 + row) * 20 + uu] + (float)gxr[q][1];
                    float gpre = ep[(2 * 128 + row) * 20 + uu] + ep[(6 * 128 + row) * 20 + uu] + (float)gxr[q][2];
                    float opre = ep[(3 * 128 + row) * 20 + uu] + ep[(7 * 128 + row) * 20 + uu] + (float)gxr[q][3];
                    float cn = sigm(fpre) * creg[q] + sigm(ipre) * tanhf(gpre);
                    creg[q] = cn;
                    hw[row * Hh + u0 + uu] = (f16)(sigm(opre) * tanhf(cn));
                }
            }
            grid_sync(bar, wg);
        }
        #pragma unroll
        for (int q = 0; q < 4; ++q) {
            int p = tid + q * 512, row = p >> 4, uu = p & 15;
            c0[row * Hh + u0 + uu] = creg[q];
        }
    } else {
        // ---------------- Layer 1: 8 units, K=2048, waves = m(2) x kq(4)
        const int wgl = wg - 64;
        const int u0  = wgl * 8;
        const int m   = w & 1, kq = w >> 1;
        const int wm  = m * 64;
        const f16* wbase = (kq < 2) ? wih1 : whh1;

        half8 wreg[16][2];                 // [j*2+kt2][nt]  (K window (kq&1)*512 + t*32)
        #pragma unroll
        for (int t = 0; t < 16; ++t)
            #pragma unroll
            for (int nt = 0; nt < 2; ++nt) {
                int c = nt * 16 + lrow;                    // col in WG: gate=c>>3, unit=c&7
                wreg[t][nt] = *(const half8*)(wbase
                    + (size_t)((c >> 3) * Hh + u0 + (c & 7)) * Hh
                    + (kq & 1) * 512 + t * 32 + koff * 8);
            }

        float creg[2];
        #pragma unroll
        for (int q = 0; q < 2; ++q) {
            int p = tid + q * 512, row = p >> 3, uu = p & 7;
            creg[q] = c1[row * Hh + u0 + uu];
        }
        const int ub = tid & 7;            // unit (same for both q)
        float b0 = bias1[u0 + ub], b1 = bias1[Hh + u0 + ub],
              b2 = bias1[2 * Hh + u0 + ub], b3 = bias1[3 * Hh + u0 + ub];

        // staging: instr t stages 8 rows (sub=(w&1)*8+t); lane l covers
        // row sub*8+(l>>3), seg l&7.  R&7 = l>>3.
        const int Rl8  = lane >> 3;
        const int seg8 = lane & 7;
        const unsigned off1 = Rl8 * 2048 + ((seg8 ^ Rl8) << 4);
        const int arow = (wm + lrow) * 128;
        const int colb_w = (kq & 1) * 1024;

        for (int i = t_begin; i < t_end; ++i) {
            int t1 = i - 1;
            if (t1 >= 0) {
                const f16* a0 = (t1 & 1) ? h0b : h0a;  // h0[t1]
                const f16* a1 = (t1 & 1) ? h1a : h1b;  // h1[t1-1]
                f16*       hw = (t1 & 1) ? h1b : h1a;  // h1[t1]
                const char* src = (const char*)(kq < 2 ? a0 : a1);

                // stage slice 0 -> buf 0
                #pragma unroll
                for (int t = 0; t < 8; ++t) {
                    int sub = (w & 1) * 8 + t;
                    gload_lds16(src + sub * 16384 + colb_w + off1,
                                smem + kq * 16384 + sub * 1024);
                }

                f32x4 acc[4][2] = {};
                int cur = 0;
                #pragma unroll
                for (int j = 0; j < 8; ++j) {
                    asm volatile("s_waitcnt vmcnt(0)" ::: "memory");
                    __syncthreads();
                    if (j < 7) {
                        int colb = colb_w + (j + 1) * 128;
                        char* lb = smem + (cur ^ 1) * 65536 + kq * 16384;
                        #pragma unroll
                        for (int t = 0; t < 8; ++t) {
                            int sub = (w & 1) * 8 + t;
                            gload_lds16(src + sub * 16384 + colb + off1, lb + sub * 1024);
                        }
                    }
                    const char* rb = (const char*)smem + cur * 65536 + kq * 16384;
                    #pragma unroll
                    for (int kt2 = 0; kt2 < 2; ++kt2) {
                        int s16 = ((kt2 * 64) ^ r34) | kxy;
                        half8 a[4];
                        #pragma unroll
                        for (int mt = 0; mt < 4; ++mt)
                            a[mt] = *(const half8*)(rb + arow + mt * 2048 + s16);
                        #pragma unroll
                        for (int mt = 0; mt < 4; ++mt) {
                            acc[mt][0] = __builtin_amdgcn_mfma_f32_16x16x32_f16(a[mt], wreg[j * 2 + kt2][0], acc[mt][0], 0, 0, 0);
                            acc[mt][1] = __builtin_amdgcn_mfma_f32_16x16x32_f16(a[mt], wreg[j * 2 + kt2][1], acc[mt][1], 0, 0, 0);
                        }
                    }
                    cur ^= 1;
                }
                __syncthreads();
                // ep[((kq*4+g)*128+row)*11 + unit]
                #pragma unroll
                for (int mt = 0; mt < 4; ++mt)
                    #pragma unroll
                    for (int nt = 0; nt < 2; ++nt) {
                        int c = nt * 16 + lrow;
                        int g = c >> 3, uu = c & 7;
                        int rowb = wm + mt * 16 + koff * 4;
                        #pragma unroll
                        for (int r = 0; r < 4; ++r)
                            ep[((kq * 4 + g) * 128 + rowb + r) * 11 + uu] = acc[mt][nt][r];
                    }
                __syncthreads();
                #pragma unroll
                for (int q = 0; q < 2; ++q) {
                    int p = tid + q * 512, row = p >> 3, uu = p & 7;
                    float ipre = ep[(0 * 128 + row) * 11 + uu] + ep[(4 * 128 + row) * 11 + uu]
                               + ep[(8 * 128 + row) * 11 + uu] + ep[(12 * 128 + row) * 11 + uu] + b0;
                    float fpre = ep[(1 * 128 + row) * 11 + uu] + ep[(5 * 128 + row) * 11 + uu]
                               + ep[(9 * 128 + row) * 11 + uu] + ep[(13 * 128 + row) * 11 + uu] + b1;
                    float gpre = ep[(2 * 128 + row) * 11 + uu] + ep[(6 * 128 + row) * 11 + uu]
                               + ep[(10 * 128 + row) * 11 + uu] + ep[(14 * 128 + row) * 11 + uu] + b2;
                    float opre = ep[(3 * 128 + row) * 11 + uu] + ep[(7 * 128 + row) * 11 + uu]
                               + ep[(11 * 128 + row) * 11 + uu] + ep[(15 * 128 + row) * 11 + uu] + b3;
                    float cn = sigm(fpre) * creg[q] + sigm(ipre) * tanhf(gpre);
                    creg[q] = cn;
                    float hn = sigm(opre) * tanhf(cn);
                    hw[row * Hh + u0 + uu] = (f16)hn;
                    out[(size_t)row * (Ss * Hh) + (size_t)t1 * Hh + u0 + uu] = hn;
                }
            }
            grid_sync(bar, wg);
        }
        #pragma unroll
        for (int q = 0; q < 2; ++q) {
            int p = tid + q * 512, row = p >> 3, uu = p & 7;
            c1[row * Hh + u0 + uu] = creg[q];
        }
    }
}

// ---------------------------------------------------------------------------
extern "C" void kernel_launch(void* const* d_in, const int* in_sizes, int n_in,
                              void* d_out, int out_size, void* d_ws, size_t ws_size,
                              hipStream_t stream) {
    const int*   x      = (const int*)  d_in[0];
    const float* emb    = (const float*)d_in[1];
    const float* proj_w = (const float*)d_in[2];
    const float* proj_b = (const float*)d_in[3];
    const float* W_ih0  = (const float*)d_in[4];
    const float* W_hh0  = (const float*)d_in[5];
    const float* b_ih0  = (const float*)d_in[6];
    const float* b_hh0  = (const float*)d_in[7];
    const float* W_ih1  = (const float*)d_in[8];
    const float* W_hh1  = (const float*)d_in[9];
    const float* b_ih1  = (const float*)d_in[10];
    const float* b_hh1  = (const float*)d_in[11];
    float* out = (float*)d_out;

    char* ws = (char*)d_ws;
    f16* emb_sum = (f16*)(ws);                               // 32 MB [S,B,E]
    f16* x_in    = (f16*)(ws + 33554432ull);                 // 32 MB [S,B,E]
    f16* gates   = (f16*)(ws + 67108864ull);                 // 128 MB (128-step chunk)
    char* wp     = ws + 201326592ull;
    f16* pw_f   = (f16*)wp; wp += (size_t)Ee * Ee * 2;
    f16* wih0_f = (f16*)wp; wp += (size_t)FourH * Ee * 2;
    f16* whh0_f = (f16*)wp; wp += (size_t)FourH * Hh * 2;
    f16* wih1_f = (f16*)wp; wp += (size_t)FourH * Hh * 2;
    f16* whh1_f = (f16*)wp; wp += (size_t)FourH * Hh * 2;
    float* bias0 = (float*)wp; wp += FourH * 4;
    float* bias1 = (float*)wp; wp += FourH * 4;
    char* zbase = wp;
    f16*   h0a = (f16*)wp;   wp += (size_t)Bb * Hh * 2;
    f16*   h0b = (f16*)wp;   wp += (size_t)Bb * Hh * 2;
    f16*   h1a = (f16*)wp;   wp += (size_t)Bb * Hh * 2;
    f16*   h1b = (f16*)wp;   wp += (size_t)Bb * Hh * 2;
    float* c0  = (float*)wp; wp += (size_t)Bb * Hh * 4;
    float* c1  = (float*)wp; wp += (size_t)Bb * Hh * 4;
    unsigned* bar = (unsigned*)wp; wp += 4096;               // 2-level barrier counters
    size_t zbytes = (size_t)(wp - zbase);

    // Prologue: converts, biases, zero state+barrier
    cvt_f16_kernel<<<512, 256, 0, stream>>>(proj_w, pw_f,   Ee * Ee);
    cvt_f16_kernel<<<512, 256, 0, stream>>>(W_ih0,  wih0_f, FourH * Ee);
    cvt_f16_kernel<<<512, 256, 0, stream>>>(W_hh0,  whh0_f, FourH * Hh);
    cvt_f16_kernel<<<512, 256, 0, stream>>>(W_ih1,  wih1_f, FourH * Hh);
    cvt_f16_kernel<<<512, 256, 0, stream>>>(W_hh1,  whh1_f, FourH * Hh);
    bias_combine_kernel<<<32, 256, 0, stream>>>(b_ih0, b_hh0, b_ih1, b_hh1, bias0, bias1);
    hipMemsetAsync(zbase, 0, zbytes, stream);

    // Embedding + input projection (time-major)
    emb_kernel<<<Mrows, 256, 0, stream>>>(x, emb, emb_sum);
    gemm_bt_kernel<<<dim3(Ee / BN, Mrows / BM), 256, 0, stream>>>(
        emb_sum, pw_f, proj_b, x_in, Mrows, Ee, Ee);

    // Two half-sequence passes: gates0 GEMM chunk + cooperative scan
    const int CM = Mrows / 2;   // 16384 rows = 128 steps

    for (int half = 0; half < 2; ++half) {
        gemm_bt_kernel<<<dim3(FourH / BN, CM / BM), 256, 0, stream>>>(
            x_in + (size_t)half * CM * Ee, wih0_f, bias0, gates, CM, FourH, Ee);
        int tb = half * 128;
        int te = (half == 0) ? 128 : 257;   // second pass runs one extra L1-only iter
        const f16* gxp = gates;
        void* args[] = { (void*)&gxp, (void*)&tb, (void*)&te,
                         (void*)&wih1_f, (void*)&whh0_f, (void*)&whh1_f, (void*)&bias1,
                         (void*)&h0a, (void*)&h0b, (void*)&h1a, (void*)&h1b,
                         (void*)&c0, (void*)&c1, (void*)&out, (void*)&bar };
        hipLaunchCooperativeKernel((const void*)scan_kernel, dim3(NBLK), dim3(512),
                                   args, 0, stream);
    }
}